// Round 13
// baseline (257.062 us; speedup 1.0000x reference)
//
#include <hip/hip_runtime.h>
#include <math.h>

#define BATCH 2
#define LSEQ 16384
#define DM 60
#define DI 120
#define NCH 512
#define TCH 32    // LSEQ / NCH (pass-1/2 chunk)
#define HH 128
#define WW 128

typedef __attribute__((ext_vector_type(8))) short bhalf8;
typedef __attribute__((ext_vector_type(4))) short short4v;
typedef __attribute__((ext_vector_type(4))) float f32x4;

__device__ __forceinline__ float sigmoidf_(float x){ return __builtin_amdgcn_rcpf(1.0f + __expf(-x)); }
__device__ __forceinline__ float siluf_(float x){ return x * sigmoidf_(x); }
__device__ __forceinline__ float softplusf_(float x){ return (x > 20.0f) ? x : __logf(1.0f + __expf(x)); }
__device__ __forceinline__ short f2b(float f){   // RNE fp32->bf16 (finite inputs)
  union{float f; unsigned u;} v; v.f = f;
  unsigned r = (v.u + 0x7fffu + ((v.u >> 16) & 1u)) >> 16;
  return (short)r;
}
__device__ __forceinline__ float b2f(short s){
  union{float f; unsigned u;} v; v.u = ((unsigned)(unsigned short)s) << 16; return v.f;
}

// p[n] = r^(n+1) for n<8
__device__ __forceinline__ void powers8(float r, float* p){
  p[0] = r;
  #pragma unroll
  for (int n = 1; n < 8; n++) p[n] = p[(n-1)>>1] * p[n>>1];
}

// ====== weight pre-pack: ipB = (lw∘ipw) bf16 [l][240][64]; xpB bf16 [l][48][128];
// ====== opB bf16 [l][64][128]; c01[l][240][2]; conv2d wB[tap][co64][ci64] (merged k_wB)
__global__ __launch_bounds__(256) void k_pack(
    const float* __restrict__ ipw, const float* __restrict__ xpw,
    const float* __restrict__ opw, const float* __restrict__ c2w,
    const float* __restrict__ lnw, const float* __restrict__ lnb,
    short* __restrict__ pk, float* __restrict__ c01, short* __restrict__ wB)
{
  int i = blockIdx.x*256 + threadIdx.x;
  if (i < 2*240*64){
    int l = i / (240*64);
    int rem = i % (240*64);
    int n = rem / 64, k = rem % 64;
    float v = (k < 60) ? ipw[(size_t)l*14400 + n*60 + k] * lnw[l*60 + k] : 0.f;
    pk[i] = f2b(v);
  } else if (i < 30720 + 2*48*128){
    int j = i - 30720;
    int l = j / (48*128);
    int rem = j % (48*128);
    int n = rem / 128, k = rem % 128;
    float v = (n < 36 && k < 120) ? xpw[(size_t)l*36*120 + n*120 + k] : 0.f;
    pk[i] = f2b(v);
  } else if (i < 43008 + 480){
    int j = i - 43008;
    int l = j / 240, n = j % 240;
    float c1 = 0.f, c0 = 0.f;
    for (int k = 0; k < 60; k++){
      float w = ipw[(size_t)l*14400 + n*60 + k];
      c1 += lnw[l*60+k] * w;
      c0 += lnb[l*60+k] * w;
    }
    c01[(l*240 + n)*2 + 0] = c1;
    c01[(l*240 + n)*2 + 1] = c0;
  } else if (i < 43488 + 2*64*128){
    int j = i - 43488;
    int l = j / 8192;
    int rem = j % 8192;
    int n = rem / 128, k = rem % 128;
    float v = (n < 60 && k < 120) ? opw[(size_t)l*7200 + n*120 + k] : 0.f;
    pk[43008 + j] = f2b(v);
  } else if (i < 59872 + 9*64*64){
    int j = i - 59872;
    int ci = j & 63, co = (j >> 6) & 63, tap = j >> 12;
    float v = 0.f;
    if (co < 60 && ci < 60) v = c2w[((size_t)co*60 + ci)*9 + tap];
    wB[j] = f2b(v);
  }
}

// ====== fused [LN-folded in_proj](MFMA) + conv1d + x_proj(MFMA) + dt_proj + chunk-scan
// ====== 32 rows = ONE scan chunk per block; halo 3; 1024 blocks; 512 thr (8 waves).
// ====== Phase 6 also dumps the 16-step (A_half,B_half) pair for scan3o's half-chunks.
__global__ __launch_bounds__(512) void k_lnxp(
    const float* __restrict__ srcf, const short* __restrict__ srcb,
    const short* __restrict__ ipB,   // [240][64] bf16 (lw-folded)
    const float* __restrict__ c01,   // [240][2] fp32 {c1,c0} (read from L2)
    const float* __restrict__ cw, const float* __restrict__ cb,
    const short* __restrict__ xpB,   // [48][128] bf16
    const float* __restrict__ dtw, const float* __restrict__ dtb,
    const float* __restrict__ A_log,
    short* __restrict__ zs, short* __restrict__ xcg,
    short* __restrict__ delta, short* __restrict__ BCg,
    float* __restrict__ ap, float* __restrict__ he,
    float* __restrict__ ah, float* __restrict__ bh)
{
  __shared__ __align__(16) char smem[65056];
  short* XB   = (short*)smem;            // [48][72] bf16 (phases 0-2); xcB aliases
  short* xcB  = (short*)smem;            // [32][136] bf16 (phase 3+)
  short* xinB = (short*)(smem + 8704);   // [48][136] bf16 (dead after phase 3)
  float* delLf= (float*)(smem + 8704);   // [32][120] fp32 delta (aliases xinB, phase 5+)
  float* xcf  = (float*)(smem + 24064);  // [32][120] fp32 xc for scan (phase 3+)
  float* BLf  = (float*)(smem + 39424);  // [32][16] fp32 B for scan
  short* BCL  = (short*)(smem + 41472);  // [32][32] bf16 (global dump)
  float* stats= (float*)(smem + 43520);  // [48][2]: {mu, rs}
  float* dtsh = (float*)(smem + 43904);  // [32][4]
  float* cwL  = (float*)(smem + 44416);  // [120][4]
  float* Wd5T = (float*)(smem + 46336);  // [4][120] (transposed dt_proj_w)
  float* cbL  = (float*)(smem + 48256);  // [120]
  float* bdL  = (float*)(smem + 48736);  // [120]
  float* A20L = (float*)(smem + 49216);  // [120] per-channel -exp(A_log[d][0])*log2e
  float* rL   = (float*)(smem + 49696);  // [32][120] fp32 exp2(del*A20)
  const int tid = threadIdx.x;
  const int wave = tid >> 6, lane = tid & 63;
  const int m = lane & 15, quad = lane >> 4;
  const int row0 = blockIdx.x * 32;
  const int seq0 = (row0 / LSEQ) * LSEQ;
  // phase 0: consts + vectorized staging of raw X (bf16); rows 0..47, valid r<35
  if (tid < 480){ cwL[tid] = cw[tid]; Wd5T[(tid & 3)*120 + (tid >> 2)] = dtw[tid]; }
  if (tid < 120){
    cbL[tid] = cb[tid]; bdL[tid] = dtb[tid];
    A20L[tid] = -__expf(A_log[tid*16]) * 1.44269504f;
  }
  for (int i = tid; i < 48*16; i += 512){
    int r = i >> 4, g = i & 15;
    int grow = row0 - 3 + r;
    short4v o = {0,0,0,0};
    if (g < 15 && r < 35 && grow >= seq0){
      if (srcb){
        o = *(const short4v*)&srcb[(size_t)grow*60 + g*4];
      } else {
        float4 f = *(const float4*)&srcf[(size_t)grow*60 + g*4];
        o.x = f2b(f.x); o.y = f2b(f.y); o.z = f2b(f.z); o.w = f2b(f.w);
      }
    }
    *(short4v*)&XB[r*72 + g*4] = o;
  }
  __syncthreads();
  // phase 1: row stats (mu, rsqrt) via 16-lane shuffle reduction (cols 60-63 zero pad)
  {
    const int sub = lane >> 4;
    const int li  = lane & 15;
    #pragma unroll
    for (int it = 0; it < 2; it++){
      int r = it*32 + wave*4 + sub;
      if (r < 48){
        short4v x4 = *(const short4v*)&XB[r*72 + li*4];
        float f0 = b2f(x4.x), f1 = b2f(x4.y), f2 = b2f(x4.z), f3 = b2f(x4.w);
        float sx = (f0 + f1) + (f2 + f3);
        float sq = (f0*f0 + f1*f1) + (f2*f2 + f3*f3);
        #pragma unroll
        for (int off = 1; off < 16; off <<= 1){
          sx += __shfl_xor(sx, off);
          sq += __shfl_xor(sq, off);
        }
        if (li == 0){
          float mu = sx * (1.0f/60.0f);
          float var = fmaxf(sq * (1.0f/60.0f) - mu*mu, 0.f);
          stats[r*2 + 0] = mu;
          stats[r*2 + 1] = rsqrtf(var + 1e-5f);
        }
      }
    }
  }
  __syncthreads();
  // phase 2: in_proj MFMA (3 mtiles x 15 ntiles over 8 waves) + LN fixup
  for (int t = wave; t < 45; t += 8){
    int mtile = t / 15, ntile = t % 15;
    f32x4 acc = {0.f,0.f,0.f,0.f};
    #pragma unroll
    for (int ks = 0; ks < 2; ks++){
      bhalf8 a = *(const bhalf8*)&XB[(mtile*16 + m)*72 + ks*32 + quad*8];
      bhalf8 b = *(const bhalf8*)&ipB[(ntile*16 + m)*64 + ks*32 + quad*8];
      acc = __builtin_amdgcn_mfma_f32_16x16x32_bf16(a, b, acc, 0, 0, 0);
    }
    int n = ntile*16 + m;
    float2 cc = *(const float2*)&c01[n*2];
    float c1v = cc.x, c0v = cc.y;
    #pragma unroll
    for (int reg = 0; reg < 4; reg++){
      int r = mtile*16 + quad*4 + reg;
      int grow = row0 - 3 + r;
      bool valid = (r < 35) && (grow >= seq0);
      float mu = stats[r*2], rs = stats[r*2+1];
      float val = rs*(acc[reg] - mu*c1v) + c0v;
      if (!valid) val = 0.f;
      if (n < 120){
        xinB[r*136 + n] = f2b(val);
      } else if (r >= 3 && r < 35){
        zs[(size_t)(row0 - 3 + r)*120 + (n - 120)] = f2b(siluf_(val));
      }
    }
  }
  __syncthreads();
  // phase 3: conv1d(4 taps)+silu -> xcB bf16 + xcf fp32 (K-pad 120..127 = 0)
  for (int i = tid; i < 960; i += 512){
    int r = i/30, c4 = (i%30)*4;
    float4 cbv = *(const float4*)&cbL[c4];
    float4 w0 = *(const float4*)&cwL[(c4+0)*4];
    float4 w1 = *(const float4*)&cwL[(c4+1)*4];
    float4 w2 = *(const float4*)&cwL[(c4+2)*4];
    float4 w3 = *(const float4*)&cwL[(c4+3)*4];
    short4v x0 = *(const short4v*)&xinB[(r+0)*136 + c4];
    short4v x1 = *(const short4v*)&xinB[(r+1)*136 + c4];
    short4v x2 = *(const short4v*)&xinB[(r+2)*136 + c4];
    short4v x3 = *(const short4v*)&xinB[(r+3)*136 + c4];
    float a0 = cbv.x + w0.x*b2f(x0.x) + w0.y*b2f(x1.x) + w0.z*b2f(x2.x) + w0.w*b2f(x3.x);
    float a1 = cbv.y + w1.x*b2f(x0.y) + w1.y*b2f(x1.y) + w1.z*b2f(x2.y) + w1.w*b2f(x3.y);
    float a2 = cbv.z + w2.x*b2f(x0.z) + w2.y*b2f(x1.z) + w2.z*b2f(x2.z) + w2.w*b2f(x3.z);
    float a3 = cbv.w + w3.x*b2f(x0.w) + w3.y*b2f(x1.w) + w3.z*b2f(x2.w) + w3.w*b2f(x3.w);
    a0 = siluf_(a0); a1 = siluf_(a1); a2 = siluf_(a2); a3 = siluf_(a3);
    float4 fo; fo.x = a0; fo.y = a1; fo.z = a2; fo.w = a3;
    *(float4*)&xcf[r*120 + c4] = fo;
    short4v o;
    o.x = f2b(a0); o.y = f2b(a1); o.z = f2b(a2); o.w = f2b(a3);
    *(short4v*)&xcB[r*136 + c4] = o;
  }
  for (int i = tid; i < 32*8; i += 512)
    xcB[(i >> 3)*136 + 120 + (i & 7)] = 0;
  __syncthreads();
  // phase 4: x_proj MFMA: 2 mtiles x 3 ntiles = 6 tiles; K=128
  for (int t = wave; t < 6; t += 8){
    int mtile = t / 3, ntile = t % 3;
    f32x4 acc = {0.f,0.f,0.f,0.f};
    #pragma unroll
    for (int ks = 0; ks < 4; ks++){
      bhalf8 a = *(const bhalf8*)&xcB[(mtile*16 + m)*136 + ks*32 + quad*8];
      bhalf8 b = *(const bhalf8*)&xpB[(ntile*16 + m)*128 + ks*32 + quad*8];
      acc = __builtin_amdgcn_mfma_f32_16x16x32_bf16(a, b, acc, 0, 0, 0);
    }
    int n = ntile*16 + m;
    #pragma unroll
    for (int reg = 0; reg < 4; reg++){
      int r = mtile*16 + quad*4 + reg;
      float val = acc[reg];
      if (n < 4)        dtsh[r*4 + n] = val;
      else if (n < 36){
        BCL[r*32 + (n - 4)] = f2b(val);
        if (n < 20) BLf[r*16 + (n - 4)] = val;
      }
    }
  }
  __syncthreads();
  // phase 5: dt_proj + softplus -> delLf fp32 + rL = exp2(del*A20) (parallel exps)
  for (int i = tid; i < 960; i += 512){
    int row = i/30, c4 = (i%30)*4;
    float4 t4 = *(const float4*)&dtsh[row*4];
    float4 w0 = *(const float4*)&Wd5T[0*120 + c4];
    float4 w1 = *(const float4*)&Wd5T[1*120 + c4];
    float4 w2 = *(const float4*)&Wd5T[2*120 + c4];
    float4 w3 = *(const float4*)&Wd5T[3*120 + c4];
    float4 bb = *(const float4*)&bdL[c4];
    float4 dd;
    dd.x = softplusf_(bb.x + t4.x*w0.x + t4.y*w1.x + t4.z*w2.x + t4.w*w3.x);
    dd.y = softplusf_(bb.y + t4.x*w0.y + t4.y*w1.y + t4.z*w2.y + t4.w*w3.y);
    dd.z = softplusf_(bb.z + t4.x*w0.z + t4.y*w1.z + t4.z*w2.z + t4.w*w3.z);
    dd.w = softplusf_(bb.w + t4.x*w0.w + t4.y*w1.w + t4.z*w2.w + t4.w*w3.w);
    *(float4*)&delLf[row*120 + c4] = dd;
    float4 aa = *(const float4*)&A20L[c4];
    float4 rr4;
    rr4.x = exp2f(dd.x * aa.x);
    rr4.y = exp2f(dd.y * aa.y);
    rr4.z = exp2f(dd.z * aa.z);
    rr4.w = exp2f(dd.w * aa.w);
    *(float4*)&rL[row*120 + c4] = rr4;
    short4v o;
    o.x = f2b(dd.x); o.y = f2b(dd.y); o.z = f2b(dd.z); o.w = f2b(dd.w);
    *(short4v*)&delta[(size_t)(row0 + row)*120 + c4] = o;
  }
  __syncthreads();
  // ---- no more barriers below ----
  // dumps issued BEFORE the serial scan so the stores fly underneath it
  for (int i = tid; i < 960; i += 512){
    int r = i/30, off = (i%30)*4;
    *(short4v*)&xcg[(size_t)(row0 + r)*120 + off] = *(const short4v*)&xcB[r*136 + off];
  }
  for (int i = tid; i < 256; i += 512)
    *(short4v*)&BCg[(size_t)row0*32 + i*4] = *(const short4v*)&BCL[i*4];
  // phase 6: fused scan pass 1 — 4 threads/channel, 4 states each; exp-free fastpath.
  // At t==16 dumps the half-chunk (A,B) pair for scan3o's half-chunk bridging.
  if (tid < 480){
    const int d = tid >> 2, q = tid & 3, n0 = q << 2;
    const int b = row0 / LSEQ;
    const int cglob = (row0 % LSEQ) >> 5;
    float A2[4], h[4];
    const float A20 = A20L[d];
    #pragma unroll
    for (int n = 0; n < 4; n++){
      A2[n] = -__expf(A_log[d*16 + n0 + n]) * 1.44269504f;
      h[n] = 0.f;
    }
    bool fastp = true;
    #pragma unroll
    for (int n = 0; n < 4; n++)
      fastp = fastp && (fabsf(A2[n] - (n0+n+1)*A20) <= 1e-4f*fabsf(A2[n]));
    int fp = fastp ? 1 : 0;
    fp &= __shfl_xor(fp, 1);
    fp &= __shfl_xor(fp, 2);    // quad-uniform fastpath decision
    const int sh1 = q & 1, sh2 = q & 2;
    int base = (cglob*BATCH + b)*(DI*16) + d*16 + n0;
    if (fp){
      float P = 1.f;
      for (int t = 0; t < 32; t += 2){
        if (t == 16){
          float q1 = P*P, q2 = q1*P, q3 = q1*q1;
          float sQ = sh1 ? q3 : 1.0f; if (sh2) sQ *= q3*q3;
          float am[4] = {sQ*P, sQ*q1, sQ*q2, sQ*q3};
          *(float4*)&ah[base] = *(float4*)&am[0];
          *(float4*)&bh[base] = *(float4*)&h[0];
        }
        float d1 = delLf[t*120 + d],     d2 = delLf[(t+1)*120 + d];
        float x1 = xcf[t*120 + d],       x2 = xcf[(t+1)*120 + d];
        float dx1 = d1*x1, dx2 = d2*x2;
        float r2s = rL[(t+1)*120 + d];
        float rr  = rL[t*120 + d] * r2s;       // r1*r2, no exp on serial path
        P *= rr;
        float c1 = rr*rr, c2 = c1*rr, c3 = c1*c1;
        float sc = sh1 ? c3 : 1.0f; if (sh2) sc *= c3*c3;
        float p1 = r2s*r2s, p2 = p1*r2s, p3 = p1*p1;
        float s2 = sh1 ? p3 : 1.0f; if (sh2) s2 *= p3*p3;
        float4 b1 = *(const float4*)&BLf[t*16 + n0];
        float4 b2 = *(const float4*)&BLf[(t+1)*16 + n0];
        float ad0 = (s2*r2s)*dx1*b1.x + dx2*b2.x;
        float ad1 = (s2*p1 )*dx1*b1.y + dx2*b2.y;
        float ad2 = (s2*p2 )*dx1*b1.z + dx2*b2.z;
        float ad3 = (s2*p3 )*dx1*b1.w + dx2*b2.w;
        h[0] = (sc*rr)*h[0] + ad0;
        h[1] = (sc*c1)*h[1] + ad1;
        h[2] = (sc*c2)*h[2] + ad2;
        h[3] = (sc*c3)*h[3] + ad3;
      }
      float P1 = P*P;
      float P2 = P1*P, P3 = P1*P1;
      float sP = sh1 ? P3 : 1.0f;
      if (sh2) sP *= P3*P3;
      float apv[4] = {sP*P, sP*P1, sP*P2, sP*P3};
      *(float4*)&ap[base] = *(float4*)&apv[0];
      *(float4*)&he[base] = *(float4*)&h[0];
    } else {
      float apv[4] = {1.f,1.f,1.f,1.f};
      for (int t = 0; t < 32; t++){
        if (t == 16){
          *(float4*)&ah[base] = *(float4*)&apv[0];
          *(float4*)&bh[base] = *(float4*)&h[0];
        }
        float del = delLf[t*120 + d];
        float dx = del * xcf[t*120 + d];
        #pragma unroll
        for (int n = 0; n < 4; n++){
          float dA = exp2f(del * A2[n]);
          apv[n] *= dA;
          h[n] = dA*h[n] + dx*BLf[t*16 + n0 + n];
        }
      }
      *(float4*)&ap[base] = *(float4*)&apv[0];
      *(float4*)&he[base] = *(float4*)&h[0];
    }
  }
}

// =============== scan pass 2: hierarchical block-parallel chunk scan ===============
__global__ __launch_bounds__(256) void k_scan2(float* __restrict__ ap, const float* __restrict__ he)
{
  __shared__ float aggA[16*17];
  __shared__ float aggB[16*17];
  const int tid = threadIdx.x;
  const int n = tid & 15, j = tid >> 4;
  const int sbase = blockIdx.x*16 + n;
  const int stride = BATCH*DI*16;
  {
    float A = 1.f, B = 0.f;
    int idx = (j*32)*stride + sbase;
    #pragma unroll 4
    for (int k = 0; k < 32; k++){
      float a = ap[idx], h = he[idx];
      B = a*B + h;
      A *= a;
      idx += stride;
    }
    aggA[n*17 + j] = A;
    aggB[n*17 + j] = B;
  }
  __syncthreads();
  if (tid < 16){
    float B = 0.f;
    #pragma unroll
    for (int jj = 0; jj < 16; jj++){
      float Af = aggA[tid*17 + jj];
      float Bf = aggB[tid*17 + jj];
      aggB[tid*17 + jj] = B;
      B = Af*B + Bf;
    }
  }
  __syncthreads();
  {
    float H = aggB[n*17 + j];
    int idx = (j*32)*stride + sbase;
    #pragma unroll 4
    for (int k = 0; k < 32; k++){
      float a = ap[idx], h = he[idx];
      ap[idx] = H;
      H = a*H + h;
      idx += stride;
    }
  }
}

// =============== scan pass 3 + out_proj: HALF-chunks (16 rows), 2048 blocks, 256 thr ===============
__global__ __launch_bounds__(256) void k_scan3o(
    const short* __restrict__ delta, const short* __restrict__ xc,
    const short* __restrict__ BCg, const short* __restrict__ zs,
    const float* __restrict__ h0, const float* __restrict__ Ah,
    const float* __restrict__ Bh, const float* __restrict__ A_log,
    const float* __restrict__ Dsk, const short* __restrict__ opB,
    short* __restrict__ hout)
{
  __shared__ float BCl[16*32];
  __shared__ __align__(16) short yL[16*136];   // bf16 y, K-padded to 128 (+stride pad)
  __shared__ __align__(16) short dL[16*120];   // staged delta
  __shared__ __align__(16) short xL[16*120];   // staged xc
  __shared__ __align__(16) short zL[16*120];   // staged zs
  const int tid = threadIdx.x;
  const int wave = tid >> 6, lane = tid & 63;
  const int m = lane & 15, quad = lane >> 4;
  const int blk = blockIdx.x;
  const int hc = blk & 1;
  const int c  = (blk >> 1) % NCH;
  const int b  = blk >> 10;               // / (NCH*2)
  const size_t rowbase = (size_t)b*LSEQ + (size_t)c*TCH + (size_t)hc*16;
  // cooperative staging: coalesced, all loads in flight
  for (int i = tid; i < 480; i += 256)
    *(short4v*)&dL[i*4] = *(const short4v*)&delta[rowbase*DI + i*4];
  for (int i = tid; i < 480; i += 256)
    *(short4v*)&xL[i*4] = *(const short4v*)&xc[rowbase*DI + i*4];
  for (int i = tid; i < 480; i += 256)
    *(short4v*)&zL[i*4] = *(const short4v*)&zs[rowbase*DI + i*4];
  for (int i = tid; i < 128; i += 256){    // 512 floats / 4
    short4v v = *(const short4v*)&BCg[rowbase*32 + i*4];
    float4 f; f.x = b2f(v.x); f.y = b2f(v.y); f.z = b2f(v.z); f.w = b2f(v.w);
    *(float4*)&BCl[i*4] = f;
  }
  for (int i = tid; i < 64; i += 256){    // zero K-pad cols 120..135
    short4v z = {0,0,0,0};
    *(short4v*)&yL[(i >> 2)*136 + 120 + (i & 3)*4] = z;
  }
  __syncthreads();
  // scan: 2 threads per channel, 8 states each; 16 serial steps; pair C-dot via shfl
  if (tid < 240){
    const int d = tid >> 1, half = tid & 1, n0 = half << 3;
    float A2[8], h[8];
    const int base = (c*BATCH + b)*(DI*16) + d*16 + n0;
    const float A20 = -__expf(A_log[d*16]) * 1.44269504f;
    // h start: half 0 = chunk h0; half 1 = Ah*h0 + Bh (exact scan composition)
    float4 h0a = *(const float4*)&h0[base];
    float4 h0b = *(const float4*)&h0[base + 4];
    if (hc){
      float4 Aa = *(const float4*)&Ah[base];
      float4 Ab = *(const float4*)&Ah[base + 4];
      float4 Ba = *(const float4*)&Bh[base];
      float4 Bb = *(const float4*)&Bh[base + 4];
      h[0] = Aa.x*h0a.x + Ba.x;  h[1] = Aa.y*h0a.y + Ba.y;
      h[2] = Aa.z*h0a.z + Ba.z;  h[3] = Aa.w*h0a.w + Ba.w;
      h[4] = Ab.x*h0b.x + Bb.x;  h[5] = Ab.y*h0b.y + Bb.y;
      h[6] = Ab.z*h0b.z + Bb.z;  h[7] = Ab.w*h0b.w + Bb.w;
    } else {
      h[0] = h0a.x; h[1] = h0a.y; h[2] = h0a.z; h[3] = h0a.w;
      h[4] = h0b.x; h[5] = h0b.y; h[6] = h0b.z; h[7] = h0b.w;
    }
    #pragma unroll
    for (int n = 0; n < 8; n++)
      A2[n] = -__expf(A_log[d*16 + n0 + n]) * 1.44269504f;
    bool fastp = true;
    #pragma unroll
    for (int n = 0; n < 8; n++)
      fastp = fastp && (fabsf(A2[n] - (n0+n+1)*A20) <= 1e-4f*fabsf(A2[n]));
    int fp = fastp ? 1 : 0;
    fp &= __shfl_xor(fp, 1);                 // pair-uniform fastpath decision
    const float Dv = Dsk[d];
    if (fp){
      for (int t = 0; t < 16; t++){
        float del = b2f(dL[t*120 + d]);
        float xcv = b2f(xL[t*120 + d]);
        float zv  = b2f(zL[t*120 + d]);
        float dx = del * xcv;
        float r = exp2f(del * A20);
        float p8[8]; powers8(r, p8);
        float s = half ? p8[7] : 1.0f;       // states 8..15: dA = r^8 * r^(j+1)
        float4 b0 = *(const float4*)&BCl[t*32 + n0];
        float4 b1 = *(const float4*)&BCl[t*32 + n0 + 4];
        h[0] = (s*p8[0])*h[0] + dx*b0.x;  h[1] = (s*p8[1])*h[1] + dx*b0.y;
        h[2] = (s*p8[2])*h[2] + dx*b0.z;  h[3] = (s*p8[3])*h[3] + dx*b0.w;
        h[4] = (s*p8[4])*h[4] + dx*b1.x;  h[5] = (s*p8[5])*h[5] + dx*b1.y;
        h[6] = (s*p8[6])*h[6] + dx*b1.z;  h[7] = (s*p8[7])*h[7] + dx*b1.w;
        float4 c0 = *(const float4*)&BCl[t*32 + 16 + n0];
        float4 c1 = *(const float4*)&BCl[t*32 + 20 + n0];
        float acc = h[0]*c0.x + h[1]*c0.y + h[2]*c0.z + h[3]*c0.w
                  + h[4]*c1.x + h[5]*c1.y + h[6]*c1.z + h[7]*c1.w;
        acc += __shfl_xor(acc, 1);
        if (!half) yL[t*136 + d] = f2b((acc + Dv*xcv) * zv);
      }
    } else {
      for (int t = 0; t < 16; t++){
        float del = b2f(dL[t*120 + d]);
        float xcv = b2f(xL[t*120 + d]);
        float zv  = b2f(zL[t*120 + d]);
        float dx = del * xcv;
        float acc = 0.f;
        #pragma unroll
        for (int n = 0; n < 8; n++){
          float dA = exp2f(del * A2[n]);
          h[n] = dA*h[n] + dx*BCl[t*32 + n0 + n];
          acc += h[n]*BCl[t*32 + 16 + n0 + n];
        }
        acc += __shfl_xor(acc, 1);
        if (!half) yL[t*136 + d] = f2b((acc + Dv*xcv) * zv);
      }
    }
  }
  __syncthreads();
  // out_proj via MFMA: M=16 (1 mtile), N=64 (4 ntiles, 60 valid), K=128 (120 valid)
  for (int t = wave; t < 4; t += 4){
    const int ntile = t;
    f32x4 acc = {0.f,0.f,0.f,0.f};
    #pragma unroll
    for (int ks = 0; ks < 4; ks++){
      bhalf8 a  = *(const bhalf8*)&yL[m*136 + ks*32 + quad*8];
      bhalf8 bb = *(const bhalf8*)&opB[(ntile*16 + m)*128 + ks*32 + quad*8];
      acc = __builtin_amdgcn_mfma_f32_16x16x32_bf16(a, bb, acc, 0, 0, 0);
    }
    const int n = ntile*16 + m;
    if (n < 60){
      #pragma unroll
      for (int reg = 0; reg < 4; reg++){
        int r = quad*4 + reg;
        hout[(rowbase + r)*60 + n] = f2b(acc[reg]);
      }
    }
  }
}

// =============== 3x3 SAME conv2d via bf16 MFMA + bias + residual ===============
__global__ __launch_bounds__(256) void k_conv2d(
    const short* __restrict__ hin, const short* __restrict__ wB,
    const float* __restrict__ cb, const float* __restrict__ xres,
    float* __restrict__ out)
{
  __shared__ short tile[3*66*72];
  const int tid = threadIdx.x;
  const int blk = blockIdx.x;
  const int xhalf = blk & 1;
  const int yy = (blk >> 1) & 127;
  const int b = blk >> 8;
  const int x0 = xhalf*64;
  // vectorized staging: short4 groups (60 % 4 == 0 so groups are fully valid or pad)
  for (int i = tid; i < 3*66*18; i += 256){
    int g = i % 18;
    int xx = (i / 18) % 66;
    int row = i / (18*66);
    int gy = yy - 1 + row, gx = x0 - 1 + xx;
    short4v v = {0,0,0,0};
    if (g < 15 && gy >= 0 && gy < HH && gx >= 0 && gx < WW)
      v = *(const short4v*)&hin[((size_t)b*LSEQ + gy*WW + gx)*60 + g*4];
    *(short4v*)&tile[(row*66 + xx)*72 + g*4] = v;
  }
  __syncthreads();
  const int wave = tid >> 6, lane = tid & 63;
  const int m = lane & 15, quad = lane >> 4;
  f32x4 acc0 = {0.f,0.f,0.f,0.f}, acc1 = {0.f,0.f,0.f,0.f};
  f32x4 acc2 = {0.f,0.f,0.f,0.f}, acc3 = {0.f,0.f,0.f,0.f};
  #pragma unroll
  for (int tap = 0; tap < 9; tap++){
    const int ky = tap/3, kx = tap%3;
    const short* arow = &tile[(ky*66 + wave*16 + m + kx)*72];
    const short* brow = wB + tap*4096;
    #pragma unroll
    for (int kh = 0; kh < 2; kh++){
      const int k0 = kh*32 + quad*8;
      bhalf8 a = *(const bhalf8*)(arow + k0);
      bhalf8 b0 = *(const bhalf8*)(brow + (0*16 + m)*64 + k0);
      bhalf8 b1 = *(const bhalf8*)(brow + (1*16 + m)*64 + k0);
      bhalf8 b2 = *(const bhalf8*)(brow + (2*16 + m)*64 + k0);
      bhalf8 b3 = *(const bhalf8*)(brow + (3*16 + m)*64 + k0);
      acc0 = __builtin_amdgcn_mfma_f32_16x16x32_bf16(a, b0, acc0, 0, 0, 0);
      acc1 = __builtin_amdgcn_mfma_f32_16x16x32_bf16(a, b1, acc1, 0, 0, 0);
      acc2 = __builtin_amdgcn_mfma_f32_16x16x32_bf16(a, b2, acc2, 0, 0, 0);
      acc3 = __builtin_amdgcn_mfma_f32_16x16x32_bf16(a, b3, acc3, 0, 0, 0);
    }
  }
  const size_t rowb = (size_t)b*LSEQ + yy*WW + x0;
  f32x4 accs[4] = {acc0, acc1, acc2, acc3};
  #pragma unroll
  for (int nt = 0; nt < 4; nt++){
    int co = nt*16 + m;
    if (co < 60){
      float bias = cb[co];
      #pragma unroll
      for (int reg = 0; reg < 4; reg++){
        int px = wave*16 + quad*4 + reg;
        size_t o = (rowb + px)*60 + co;
        out[o] = accs[nt][reg] + bias + xres[o];
      }
    }
  }
}

extern "C" void kernel_launch(void* const* d_in, const int* in_sizes, int n_in,
                              void* d_out, int out_size, void* d_ws, size_t ws_size,
                              hipStream_t stream)
{
  const float* x      = (const float*)d_in[0];
  const float* ln_w   = (const float*)d_in[1];
  const float* ln_b   = (const float*)d_in[2];
  const float* ipw    = (const float*)d_in[3];
  const float* cw     = (const float*)d_in[4];
  const float* cb1    = (const float*)d_in[5];
  const float* xpw    = (const float*)d_in[6];
  const float* dtw    = (const float*)d_in[7];
  const float* dtb    = (const float*)d_in[8];
  const float* A_log  = (const float*)d_in[9];
  const float* Dsk    = (const float*)d_in[10];
  const float* opw    = (const float*)d_in[11];
  const float* c2w    = (const float*)d_in[12];
  const float* c2b    = (const float*)d_in[13];
  float* out = (float*)d_out;

  char* ws = (char*)d_ws;
  size_t off = 0;
  short* zsb   = (short*)(ws + off); off += (size_t)BATCH*LSEQ*DI*2;
  short* xcb   = (short*)(ws + off); off += (size_t)BATCH*LSEQ*DI*2;
  short* dlt   = (short*)(ws + off); off += (size_t)BATCH*LSEQ*DI*2;
  short* BCg   = (short*)(ws + off); off += (size_t)BATCH*LSEQ*32*2;
  float* apb   = (float*)(ws + off); off += (size_t)NCH*BATCH*DI*16*4;
  float* heb   = (float*)(ws + off); off += (size_t)NCH*BATCH*DI*16*4;
  float* ahb   = (float*)(ws + off); off += (size_t)NCH*BATCH*DI*16*4;
  float* bhb   = (float*)(ws + off); off += (size_t)NCH*BATCH*DI*16*4;
  short* hcur  = (short*)(ws + off); off += (size_t)BATCH*LSEQ*DM*2;
  short* wBb   = (short*)(ws + off); off += (size_t)9*64*64*2;
  short* pkb   = (short*)(ws + off); off += (size_t)(2*240*64 + 2*48*128 + 2*64*128)*2;
  float* c01b  = (float*)(ws + off); off += (size_t)2*240*2*4;

  const int rows = BATCH*LSEQ;
  k_pack<<<(59872 + 9*64*64 + 255)/256, 256, 0, stream>>>(ipw, xpw, opw, c2w, ln_w, ln_b, pkb, c01b, wBb);
  for (int layer = 0; layer < 2; layer++){
    const float* srcf = (layer == 0) ? x : nullptr;
    const short* srcb = (layer == 0) ? nullptr : hcur;
    k_lnxp<<<rows/32, 512, 0, stream>>>(srcf, srcb,
                                        pkb + (size_t)layer*240*64,
                                        c01b + (size_t)layer*240*2,
                                        cw + layer*DI*4, cb1 + layer*DI,
                                        pkb + 30720 + (size_t)layer*48*128,
                                        dtw + (size_t)layer*DI*4, dtb + layer*DI,
                                        A_log + (size_t)layer*DI*16,
                                        zsb, xcb, dlt, BCg, apb, heb, ahb, bhb);
    k_scan2<<<BATCH*DI, 256, 0, stream>>>(apb, heb);
    k_scan3o<<<BATCH*NCH*2, 256, 0, stream>>>(dlt, xcb, BCg, zsb, apb, ahb, bhb,
                                              A_log + (size_t)layer*DI*16,
                                              Dsk + layer*DI, pkb + 43008 + (size_t)layer*8192, hcur);
  }
  k_conv2d<<<BATCH*HH*2, 256, 0, stream>>>(hcur, wBb, c2b, x, out);
}

// Round 14
// 252.847 us; speedup vs baseline: 1.0167x; 1.0167x over previous
//
#include <hip/hip_runtime.h>
#include <math.h>

#define BATCH 2
#define LSEQ 16384
#define DM 60
#define DI 120
#define NCH 512
#define TCH 32    // LSEQ / NCH
#define HH 128
#define WW 128

typedef __attribute__((ext_vector_type(8))) short bhalf8;
typedef __attribute__((ext_vector_type(4))) short short4v;
typedef __attribute__((ext_vector_type(4))) float f32x4;

__device__ __forceinline__ float sigmoidf_(float x){ return __builtin_amdgcn_rcpf(1.0f + __expf(-x)); }
__device__ __forceinline__ float siluf_(float x){ return x * sigmoidf_(x); }
__device__ __forceinline__ float softplusf_(float x){ return (x > 20.0f) ? x : __logf(1.0f + __expf(x)); }
__device__ __forceinline__ short f2b(float f){   // RNE fp32->bf16 (finite inputs)
  union{float f; unsigned u;} v; v.f = f;
  unsigned r = (v.u + 0x7fffu + ((v.u >> 16) & 1u)) >> 16;
  return (short)r;
}
__device__ __forceinline__ float b2f(short s){
  union{float f; unsigned u;} v; v.u = ((unsigned)(unsigned short)s) << 16; return v.f;
}

// p[n] = r^(n+1) for n<8
__device__ __forceinline__ void powers8(float r, float* p){
  p[0] = r;
  #pragma unroll
  for (int n = 1; n < 8; n++) p[n] = p[(n-1)>>1] * p[n>>1];
}

// ====== weight pre-pack: ipB = (lw∘ipw) bf16 [l][240][64]; xpB bf16 [l][48][128];
// ====== opB bf16 [l][64][128]; c01[l][240][2]; conv2d wB[tap][co64][ci64] (merged k_wB)
__global__ __launch_bounds__(256) void k_pack(
    const float* __restrict__ ipw, const float* __restrict__ xpw,
    const float* __restrict__ opw, const float* __restrict__ c2w,
    const float* __restrict__ lnw, const float* __restrict__ lnb,
    short* __restrict__ pk, float* __restrict__ c01, short* __restrict__ wB)
{
  int i = blockIdx.x*256 + threadIdx.x;
  if (i < 2*240*64){
    int l = i / (240*64);
    int rem = i % (240*64);
    int n = rem / 64, k = rem % 64;
    float v = (k < 60) ? ipw[(size_t)l*14400 + n*60 + k] * lnw[l*60 + k] : 0.f;
    pk[i] = f2b(v);
  } else if (i < 30720 + 2*48*128){
    int j = i - 30720;
    int l = j / (48*128);
    int rem = j % (48*128);
    int n = rem / 128, k = rem % 128;
    float v = (n < 36 && k < 120) ? xpw[(size_t)l*36*120 + n*120 + k] : 0.f;
    pk[i] = f2b(v);
  } else if (i < 43008 + 480){
    int j = i - 43008;
    int l = j / 240, n = j % 240;
    float c1 = 0.f, c0 = 0.f;
    for (int k = 0; k < 60; k++){
      float w = ipw[(size_t)l*14400 + n*60 + k];
      c1 += lnw[l*60+k] * w;
      c0 += lnb[l*60+k] * w;
    }
    c01[(l*240 + n)*2 + 0] = c1;
    c01[(l*240 + n)*2 + 1] = c0;
  } else if (i < 43488 + 2*64*128){
    int j = i - 43488;
    int l = j / 8192;
    int rem = j % 8192;
    int n = rem / 128, k = rem % 128;
    float v = (n < 60 && k < 120) ? opw[(size_t)l*7200 + n*120 + k] : 0.f;
    pk[43008 + j] = f2b(v);
  } else if (i < 59872 + 9*64*64){
    int j = i - 59872;
    int ci = j & 63, co = (j >> 6) & 63, tap = j >> 12;
    float v = 0.f;
    if (co < 60 && ci < 60) v = c2w[((size_t)co*60 + ci)*9 + tap];
    wB[j] = f2b(v);
  }
}

// ====== fused [LN-folded in_proj](MFMA) + conv1d + x_proj(MFMA) + dt_proj + chunk-scan
// ====== 32 rows = ONE scan chunk per block; halo 3; 1024 blocks; 512 thr (8 waves).
// ====== Phase 5 precomputes rL = exp2(del*A20) in parallel; phase 6 scan is exp-free.
__global__ __launch_bounds__(512) void k_lnxp(
    const float* __restrict__ srcf, const short* __restrict__ srcb,
    const short* __restrict__ ipB,   // [240][64] bf16 (lw-folded)
    const float* __restrict__ c01,   // [240][2] fp32 {c1,c0} (read from L2)
    const float* __restrict__ cw, const float* __restrict__ cb,
    const short* __restrict__ xpB,   // [48][128] bf16
    const float* __restrict__ dtw, const float* __restrict__ dtb,
    const float* __restrict__ A_log,
    short* __restrict__ zs, short* __restrict__ xcg,
    short* __restrict__ delta, short* __restrict__ BCg,
    float* __restrict__ ap, float* __restrict__ he)
{
  __shared__ __align__(16) char smem[65056];
  short* XB   = (short*)smem;            // [48][72] bf16 (phases 0-2); xcB aliases
  short* xcB  = (short*)smem;            // [32][136] bf16 (phase 3+)
  short* xinB = (short*)(smem + 8704);   // [48][136] bf16 (dead after phase 3)
  float* delLf= (float*)(smem + 8704);   // [32][120] fp32 delta (aliases xinB, phase 5+)
  float* xcf  = (float*)(smem + 24064);  // [32][120] fp32 xc for scan (phase 3+)
  float* BLf  = (float*)(smem + 39424);  // [32][16] fp32 B for scan
  short* BCL  = (short*)(smem + 41472);  // [32][32] bf16 (global dump)
  float* stats= (float*)(smem + 43520);  // [48][2]: {mu, rs}
  float* dtsh = (float*)(smem + 43904);  // [32][4]
  float* cwL  = (float*)(smem + 44416);  // [120][4]
  float* Wd5T = (float*)(smem + 46336);  // [4][120] (transposed dt_proj_w)
  float* cbL  = (float*)(smem + 48256);  // [120]
  float* bdL  = (float*)(smem + 48736);  // [120]
  float* A20L = (float*)(smem + 49216);  // [120] per-channel -exp(A_log[d][0])*log2e
  float* rL   = (float*)(smem + 49696);  // [32][120] fp32 exp2(del*A20)
  const int tid = threadIdx.x;
  const int wave = tid >> 6, lane = tid & 63;
  const int m = lane & 15, quad = lane >> 4;
  const int row0 = blockIdx.x * 32;
  const int seq0 = (row0 / LSEQ) * LSEQ;
  // phase 0: consts + vectorized staging of raw X (bf16); rows 0..47, valid r<35
  if (tid < 480){ cwL[tid] = cw[tid]; Wd5T[(tid & 3)*120 + (tid >> 2)] = dtw[tid]; }
  if (tid < 120){
    cbL[tid] = cb[tid]; bdL[tid] = dtb[tid];
    A20L[tid] = -__expf(A_log[tid*16]) * 1.44269504f;
  }
  for (int i = tid; i < 48*16; i += 512){
    int r = i >> 4, g = i & 15;
    int grow = row0 - 3 + r;
    short4v o = {0,0,0,0};
    if (g < 15 && r < 35 && grow >= seq0){
      if (srcb){
        o = *(const short4v*)&srcb[(size_t)grow*60 + g*4];
      } else {
        float4 f = *(const float4*)&srcf[(size_t)grow*60 + g*4];
        o.x = f2b(f.x); o.y = f2b(f.y); o.z = f2b(f.z); o.w = f2b(f.w);
      }
    }
    *(short4v*)&XB[r*72 + g*4] = o;
  }
  __syncthreads();
  // phase 1: row stats (mu, rsqrt) via 16-lane shuffle reduction (cols 60-63 zero pad)
  {
    const int sub = lane >> 4;
    const int li  = lane & 15;
    #pragma unroll
    for (int it = 0; it < 2; it++){
      int r = it*32 + wave*4 + sub;
      if (r < 48){
        short4v x4 = *(const short4v*)&XB[r*72 + li*4];
        float f0 = b2f(x4.x), f1 = b2f(x4.y), f2 = b2f(x4.z), f3 = b2f(x4.w);
        float sx = (f0 + f1) + (f2 + f3);
        float sq = (f0*f0 + f1*f1) + (f2*f2 + f3*f3);
        #pragma unroll
        for (int off = 1; off < 16; off <<= 1){
          sx += __shfl_xor(sx, off);
          sq += __shfl_xor(sq, off);
        }
        if (li == 0){
          float mu = sx * (1.0f/60.0f);
          float var = fmaxf(sq * (1.0f/60.0f) - mu*mu, 0.f);
          stats[r*2 + 0] = mu;
          stats[r*2 + 1] = rsqrtf(var + 1e-5f);
        }
      }
    }
  }
  __syncthreads();
  // phase 2: in_proj MFMA (3 mtiles x 15 ntiles over 8 waves) + LN fixup
  for (int t = wave; t < 45; t += 8){
    int mtile = t / 15, ntile = t % 15;
    f32x4 acc = {0.f,0.f,0.f,0.f};
    #pragma unroll
    for (int ks = 0; ks < 2; ks++){
      bhalf8 a = *(const bhalf8*)&XB[(mtile*16 + m)*72 + ks*32 + quad*8];
      bhalf8 b = *(const bhalf8*)&ipB[(ntile*16 + m)*64 + ks*32 + quad*8];
      acc = __builtin_amdgcn_mfma_f32_16x16x32_bf16(a, b, acc, 0, 0, 0);
    }
    int n = ntile*16 + m;
    float2 cc = *(const float2*)&c01[n*2];
    float c1v = cc.x, c0v = cc.y;
    #pragma unroll
    for (int reg = 0; reg < 4; reg++){
      int r = mtile*16 + quad*4 + reg;
      int grow = row0 - 3 + r;
      bool valid = (r < 35) && (grow >= seq0);
      float mu = stats[r*2], rs = stats[r*2+1];
      float val = rs*(acc[reg] - mu*c1v) + c0v;
      if (!valid) val = 0.f;
      if (n < 120){
        xinB[r*136 + n] = f2b(val);
      } else if (r >= 3 && r < 35){
        zs[(size_t)(row0 - 3 + r)*120 + (n - 120)] = f2b(siluf_(val));
      }
    }
  }
  __syncthreads();
  // phase 3: conv1d(4 taps)+silu -> xcB bf16 + xcf fp32 (K-pad 120..127 = 0)
  for (int i = tid; i < 960; i += 512){
    int r = i/30, c4 = (i%30)*4;
    float4 cbv = *(const float4*)&cbL[c4];
    float4 w0 = *(const float4*)&cwL[(c4+0)*4];
    float4 w1 = *(const float4*)&cwL[(c4+1)*4];
    float4 w2 = *(const float4*)&cwL[(c4+2)*4];
    float4 w3 = *(const float4*)&cwL[(c4+3)*4];
    short4v x0 = *(const short4v*)&xinB[(r+0)*136 + c4];
    short4v x1 = *(const short4v*)&xinB[(r+1)*136 + c4];
    short4v x2 = *(const short4v*)&xinB[(r+2)*136 + c4];
    short4v x3 = *(const short4v*)&xinB[(r+3)*136 + c4];
    float a0 = cbv.x + w0.x*b2f(x0.x) + w0.y*b2f(x1.x) + w0.z*b2f(x2.x) + w0.w*b2f(x3.x);
    float a1 = cbv.y + w1.x*b2f(x0.y) + w1.y*b2f(x1.y) + w1.z*b2f(x2.y) + w1.w*b2f(x3.y);
    float a2 = cbv.z + w2.x*b2f(x0.z) + w2.y*b2f(x1.z) + w2.z*b2f(x2.z) + w2.w*b2f(x3.z);
    float a3 = cbv.w + w3.x*b2f(x0.w) + w3.y*b2f(x1.w) + w3.z*b2f(x2.w) + w3.w*b2f(x3.w);
    a0 = siluf_(a0); a1 = siluf_(a1); a2 = siluf_(a2); a3 = siluf_(a3);
    float4 fo; fo.x = a0; fo.y = a1; fo.z = a2; fo.w = a3;
    *(float4*)&xcf[r*120 + c4] = fo;
    short4v o;
    o.x = f2b(a0); o.y = f2b(a1); o.z = f2b(a2); o.w = f2b(a3);
    *(short4v*)&xcB[r*136 + c4] = o;
  }
  for (int i = tid; i < 32*8; i += 512)
    xcB[(i >> 3)*136 + 120 + (i & 7)] = 0;
  __syncthreads();
  // phase 4: x_proj MFMA: 2 mtiles x 3 ntiles = 6 tiles; K=128
  for (int t = wave; t < 6; t += 8){
    int mtile = t / 3, ntile = t % 3;
    f32x4 acc = {0.f,0.f,0.f,0.f};
    #pragma unroll
    for (int ks = 0; ks < 4; ks++){
      bhalf8 a = *(const bhalf8*)&xcB[(mtile*16 + m)*136 + ks*32 + quad*8];
      bhalf8 b = *(const bhalf8*)&xpB[(ntile*16 + m)*128 + ks*32 + quad*8];
      acc = __builtin_amdgcn_mfma_f32_16x16x32_bf16(a, b, acc, 0, 0, 0);
    }
    int n = ntile*16 + m;
    #pragma unroll
    for (int reg = 0; reg < 4; reg++){
      int r = mtile*16 + quad*4 + reg;
      float val = acc[reg];
      if (n < 4)        dtsh[r*4 + n] = val;
      else if (n < 36){
        BCL[r*32 + (n - 4)] = f2b(val);
        if (n < 20) BLf[r*16 + (n - 4)] = val;
      }
    }
  }
  __syncthreads();
  // phase 5: dt_proj + softplus -> delLf fp32 + rL = exp2(del*A20) (parallel exps)
  for (int i = tid; i < 960; i += 512){
    int row = i/30, c4 = (i%30)*4;
    float4 t4 = *(const float4*)&dtsh[row*4];
    float4 w0 = *(const float4*)&Wd5T[0*120 + c4];
    float4 w1 = *(const float4*)&Wd5T[1*120 + c4];
    float4 w2 = *(const float4*)&Wd5T[2*120 + c4];
    float4 w3 = *(const float4*)&Wd5T[3*120 + c4];
    float4 bb = *(const float4*)&bdL[c4];
    float4 dd;
    dd.x = softplusf_(bb.x + t4.x*w0.x + t4.y*w1.x + t4.z*w2.x + t4.w*w3.x);
    dd.y = softplusf_(bb.y + t4.x*w0.y + t4.y*w1.y + t4.z*w2.y + t4.w*w3.y);
    dd.z = softplusf_(bb.z + t4.x*w0.z + t4.y*w1.z + t4.z*w2.z + t4.w*w3.z);
    dd.w = softplusf_(bb.w + t4.x*w0.w + t4.y*w1.w + t4.z*w2.w + t4.w*w3.w);
    *(float4*)&delLf[row*120 + c4] = dd;
    float4 aa = *(const float4*)&A20L[c4];
    float4 rr4;
    rr4.x = exp2f(dd.x * aa.x);
    rr4.y = exp2f(dd.y * aa.y);
    rr4.z = exp2f(dd.z * aa.z);
    rr4.w = exp2f(dd.w * aa.w);
    *(float4*)&rL[row*120 + c4] = rr4;
    short4v o;
    o.x = f2b(dd.x); o.y = f2b(dd.y); o.z = f2b(dd.z); o.w = f2b(dd.w);
    *(short4v*)&delta[(size_t)(row0 + row)*120 + c4] = o;
  }
  __syncthreads();
  // ---- no more barriers below ----
  // dumps issued BEFORE the serial scan so the stores fly underneath it
  for (int i = tid; i < 960; i += 512){
    int r = i/30, off = (i%30)*4;
    *(short4v*)&xcg[(size_t)(row0 + r)*120 + off] = *(const short4v*)&xcB[r*136 + off];
  }
  for (int i = tid; i < 256; i += 512)
    *(short4v*)&BCg[(size_t)row0*32 + i*4] = *(const short4v*)&BCL[i*4];
  // phase 6: fused scan pass 1 — 4 threads/channel, 4 states each; exp-free fastpath
  if (tid < 480){
    const int d = tid >> 2, q = tid & 3, n0 = q << 2;
    const int b = row0 / LSEQ;
    const int cglob = (row0 % LSEQ) >> 5;
    float A2[4], h[4];
    const float A20 = A20L[d];
    #pragma unroll
    for (int n = 0; n < 4; n++){
      A2[n] = -__expf(A_log[d*16 + n0 + n]) * 1.44269504f;
      h[n] = 0.f;
    }
    bool fastp = true;
    #pragma unroll
    for (int n = 0; n < 4; n++)
      fastp = fastp && (fabsf(A2[n] - (n0+n+1)*A20) <= 1e-4f*fabsf(A2[n]));
    int fp = fastp ? 1 : 0;
    fp &= __shfl_xor(fp, 1);
    fp &= __shfl_xor(fp, 2);    // quad-uniform fastpath decision
    const int sh1 = q & 1, sh2 = q & 2;
    int base = (cglob*BATCH + b)*(DI*16) + d*16 + n0;
    if (fp){
      float P = 1.f;
      for (int t = 0; t < 32; t += 2){
        float d1 = delLf[t*120 + d],     d2 = delLf[(t+1)*120 + d];
        float x1 = xcf[t*120 + d],       x2 = xcf[(t+1)*120 + d];
        float dx1 = d1*x1, dx2 = d2*x2;
        float r2s = rL[(t+1)*120 + d];
        float rr  = rL[t*120 + d] * r2s;       // r1*r2, no exp on serial path
        P *= rr;
        float c1 = rr*rr, c2 = c1*rr, c3 = c1*c1;
        float sc = sh1 ? c3 : 1.0f; if (sh2) sc *= c3*c3;
        float p1 = r2s*r2s, p2 = p1*r2s, p3 = p1*p1;
        float s2 = sh1 ? p3 : 1.0f; if (sh2) s2 *= p3*p3;
        float4 b1 = *(const float4*)&BLf[t*16 + n0];
        float4 b2 = *(const float4*)&BLf[(t+1)*16 + n0];
        float ad0 = (s2*r2s)*dx1*b1.x + dx2*b2.x;
        float ad1 = (s2*p1 )*dx1*b1.y + dx2*b2.y;
        float ad2 = (s2*p2 )*dx1*b1.z + dx2*b2.z;
        float ad3 = (s2*p3 )*dx1*b1.w + dx2*b2.w;
        h[0] = (sc*rr)*h[0] + ad0;
        h[1] = (sc*c1)*h[1] + ad1;
        h[2] = (sc*c2)*h[2] + ad2;
        h[3] = (sc*c3)*h[3] + ad3;
      }
      float P1 = P*P;
      float P2 = P1*P, P3 = P1*P1;
      float sP = sh1 ? P3 : 1.0f;
      if (sh2) sP *= P3*P3;
      float apv[4] = {sP*P, sP*P1, sP*P2, sP*P3};
      *(float4*)&ap[base] = *(float4*)&apv[0];
      *(float4*)&he[base] = *(float4*)&h[0];
    } else {
      float apv[4] = {1.f,1.f,1.f,1.f};
      for (int t = 0; t < 32; t++){
        float del = delLf[t*120 + d];
        float dx = del * xcf[t*120 + d];
        #pragma unroll
        for (int n = 0; n < 4; n++){
          float dA = exp2f(del * A2[n]);
          apv[n] *= dA;
          h[n] = dA*h[n] + dx*BLf[t*16 + n0 + n];
        }
      }
      *(float4*)&ap[base] = *(float4*)&apv[0];
      *(float4*)&he[base] = *(float4*)&h[0];
    }
  }
}

// =============== scan pass 2: hierarchical block-parallel chunk scan ===============
__global__ __launch_bounds__(256) void k_scan2(float* __restrict__ ap, const float* __restrict__ he)
{
  __shared__ float aggA[16*17];
  __shared__ float aggB[16*17];
  const int tid = threadIdx.x;
  const int n = tid & 15, j = tid >> 4;
  const int sbase = blockIdx.x*16 + n;
  const int stride = BATCH*DI*16;
  {
    float A = 1.f, B = 0.f;
    int idx = (j*32)*stride + sbase;
    #pragma unroll 4
    for (int k = 0; k < 32; k++){
      float a = ap[idx], h = he[idx];
      B = a*B + h;
      A *= a;
      idx += stride;
    }
    aggA[n*17 + j] = A;
    aggB[n*17 + j] = B;
  }
  __syncthreads();
  if (tid < 16){
    float B = 0.f;
    #pragma unroll
    for (int jj = 0; jj < 16; jj++){
      float Af = aggA[tid*17 + jj];
      float Bf = aggB[tid*17 + jj];
      aggB[tid*17 + jj] = B;
      B = Af*B + Bf;
    }
  }
  __syncthreads();
  {
    float H = aggB[n*17 + j];
    int idx = (j*32)*stride + sbase;
    #pragma unroll 4
    for (int k = 0; k < 32; k++){
      float a = ap[idx], h = he[idx];
      ap[idx] = H;
      H = a*H + h;
      idx += stride;
    }
  }
}

// =============== scan pass 3 + out_proj fused: 256 thr, LDS-staged inputs ===============
__global__ __launch_bounds__(256) void k_scan3o(
    const short* __restrict__ delta, const short* __restrict__ xc,
    const short* __restrict__ BCg, const short* __restrict__ zs,
    const float* __restrict__ h0, const float* __restrict__ A_log,
    const float* __restrict__ Dsk, const short* __restrict__ opB,
    short* __restrict__ hout)
{
  __shared__ float BCl[TCH*32];
  __shared__ __align__(16) short yL[TCH*136];   // bf16 y, K-padded to 128 (+stride pad)
  __shared__ __align__(16) short dL[TCH*120];   // staged delta
  __shared__ __align__(16) short xL[TCH*120];   // staged xc
  __shared__ __align__(16) short zL[TCH*120];   // staged zs
  const int tid = threadIdx.x;
  const int wave = tid >> 6, lane = tid & 63;
  const int m = lane & 15, quad = lane >> 4;
  const int c = blockIdx.x % NCH, b = blockIdx.x / NCH;
  const size_t rowbase = (size_t)b*LSEQ + (size_t)c*TCH;
  // cooperative staging: coalesced, all loads in flight (removes per-step latency)
  for (int i = tid; i < 960; i += 256)
    *(short4v*)&dL[i*4] = *(const short4v*)&delta[rowbase*DI + i*4];
  for (int i = tid; i < 960; i += 256)
    *(short4v*)&xL[i*4] = *(const short4v*)&xc[rowbase*DI + i*4];
  for (int i = tid; i < 960; i += 256)
    *(short4v*)&zL[i*4] = *(const short4v*)&zs[rowbase*DI + i*4];
  for (int i = tid; i < TCH*8; i += 256){    // 1024 elems / 4
    short4v v = *(const short4v*)&BCg[rowbase*32 + i*4];
    float4 f; f.x = b2f(v.x); f.y = b2f(v.y); f.z = b2f(v.z); f.w = b2f(v.w);
    *(float4*)&BCl[i*4] = f;
  }
  for (int i = tid; i < TCH*4; i += 256){    // zero K-pad cols 120..135
    short4v z = {0,0,0,0};
    *(short4v*)&yL[(i >> 2)*136 + 120 + (i & 3)*4] = z;
  }
  __syncthreads();
  // scan: 2 threads per channel, 8 states each; pair sums C-dot via shfl
  if (tid < 240){
    const int d = tid >> 1, half = tid & 1, n0 = half << 3;
    float A2[8], h[8];
    const int base = (c*BATCH + b)*(DI*16) + d*16 + n0;
    const float A20 = -__expf(A_log[d*16]) * 1.44269504f;
    #pragma unroll
    for (int n = 0; n < 8; n++){
      A2[n] = -__expf(A_log[d*16 + n0 + n]) * 1.44269504f;
      h[n] = h0[base + n];
    }
    bool fastp = true;
    #pragma unroll
    for (int n = 0; n < 8; n++)
      fastp = fastp && (fabsf(A2[n] - (n0+n+1)*A20) <= 1e-4f*fabsf(A2[n]));
    int fp = fastp ? 1 : 0;
    fp &= __shfl_xor(fp, 1);                 // pair-uniform fastpath decision
    const float Dv = Dsk[d];
    if (fp){
      for (int t = 0; t < TCH; t++){
        float del = b2f(dL[t*120 + d]);
        float xcv = b2f(xL[t*120 + d]);
        float zv  = b2f(zL[t*120 + d]);
        float dx = del * xcv;
        float r = exp2f(del * A20);
        float p8[8]; powers8(r, p8);
        float s = half ? p8[7] : 1.0f;       // states 8..15: dA = r^8 * r^(j+1)
        float4 b0 = *(const float4*)&BCl[t*32 + n0];
        float4 b1 = *(const float4*)&BCl[t*32 + n0 + 4];
        h[0] = (s*p8[0])*h[0] + dx*b0.x;  h[1] = (s*p8[1])*h[1] + dx*b0.y;
        h[2] = (s*p8[2])*h[2] + dx*b0.z;  h[3] = (s*p8[3])*h[3] + dx*b0.w;
        h[4] = (s*p8[4])*h[4] + dx*b1.x;  h[5] = (s*p8[5])*h[5] + dx*b1.y;
        h[6] = (s*p8[6])*h[6] + dx*b1.z;  h[7] = (s*p8[7])*h[7] + dx*b1.w;
        float4 c0 = *(const float4*)&BCl[t*32 + 16 + n0];
        float4 c1 = *(const float4*)&BCl[t*32 + 20 + n0];
        float acc = h[0]*c0.x + h[1]*c0.y + h[2]*c0.z + h[3]*c0.w
                  + h[4]*c1.x + h[5]*c1.y + h[6]*c1.z + h[7]*c1.w;
        acc += __shfl_xor(acc, 1);
        if (!half) yL[t*136 + d] = f2b((acc + Dv*xcv) * zv);
      }
    } else {
      for (int t = 0; t < TCH; t++){
        float del = b2f(dL[t*120 + d]);
        float xcv = b2f(xL[t*120 + d]);
        float zv  = b2f(zL[t*120 + d]);
        float dx = del * xcv;
        float acc = 0.f;
        #pragma unroll
        for (int n = 0; n < 8; n++){
          float dA = exp2f(del * A2[n]);
          h[n] = dA*h[n] + dx*BCl[t*32 + n0 + n];
          acc += h[n]*BCl[t*32 + 16 + n0 + n];
        }
        acc += __shfl_xor(acc, 1);
        if (!half) yL[t*136 + d] = f2b((acc + Dv*xcv) * zv);
      }
    }
  }
  __syncthreads();
  // out_proj via MFMA: M=32 (2 mtiles), N=64 (4 ntiles, 60 valid), K=128 (120 valid)
  for (int t = wave; t < 8; t += 4){
    const int mtile = t >> 2, ntile = t & 3;
    f32x4 acc = {0.f,0.f,0.f,0.f};
    #pragma unroll
    for (int ks = 0; ks < 4; ks++){
      bhalf8 a  = *(const bhalf8*)&yL[(mtile*16 + m)*136 + ks*32 + quad*8];
      bhalf8 bb = *(const bhalf8*)&opB[(ntile*16 + m)*128 + ks*32 + quad*8];
      acc = __builtin_amdgcn_mfma_f32_16x16x32_bf16(a, bb, acc, 0, 0, 0);
    }
    const int n = ntile*16 + m;
    if (n < 60){
      #pragma unroll
      for (int reg = 0; reg < 4; reg++){
        int r = mtile*16 + quad*4 + reg;
        hout[(rowbase + r)*60 + n] = f2b(acc[reg]);
      }
    }
  }
}

// =============== 3x3 SAME conv2d via bf16 MFMA + bias + residual ===============
__global__ __launch_bounds__(256) void k_conv2d(
    const short* __restrict__ hin, const short* __restrict__ wB,
    const float* __restrict__ cb, const float* __restrict__ xres,
    float* __restrict__ out)
{
  __shared__ short tile[3*66*72];
  const int tid = threadIdx.x;
  const int blk = blockIdx.x;
  const int xhalf = blk & 1;
  const int yy = (blk >> 1) & 127;
  const int b = blk >> 8;
  const int x0 = xhalf*64;
  // vectorized staging: short4 groups (60 % 4 == 0 so groups are fully valid or pad)
  for (int i = tid; i < 3*66*18; i += 256){
    int g = i % 18;
    int xx = (i / 18) % 66;
    int row = i / (18*66);
    int gy = yy - 1 + row, gx = x0 - 1 + xx;
    short4v v = {0,0,0,0};
    if (g < 15 && gy >= 0 && gy < HH && gx >= 0 && gx < WW)
      v = *(const short4v*)&hin[((size_t)b*LSEQ + gy*WW + gx)*60 + g*4];
    *(short4v*)&tile[(row*66 + xx)*72 + g*4] = v;
  }
  __syncthreads();
  const int wave = tid >> 6, lane = tid & 63;
  const int m = lane & 15, quad = lane >> 4;
  f32x4 acc0 = {0.f,0.f,0.f,0.f}, acc1 = {0.f,0.f,0.f,0.f};
  f32x4 acc2 = {0.f,0.f,0.f,0.f}, acc3 = {0.f,0.f,0.f,0.f};
  #pragma unroll
  for (int tap = 0; tap < 9; tap++){
    const int ky = tap/3, kx = tap%3;
    const short* arow = &tile[(ky*66 + wave*16 + m + kx)*72];
    const short* brow = wB + tap*4096;
    #pragma unroll
    for (int kh = 0; kh < 2; kh++){
      const int k0 = kh*32 + quad*8;
      bhalf8 a = *(const bhalf8*)(arow + k0);
      bhalf8 b0 = *(const bhalf8*)(brow + (0*16 + m)*64 + k0);
      bhalf8 b1 = *(const bhalf8*)(brow + (1*16 + m)*64 + k0);
      bhalf8 b2 = *(const bhalf8*)(brow + (2*16 + m)*64 + k0);
      bhalf8 b3 = *(const bhalf8*)(brow + (3*16 + m)*64 + k0);
      acc0 = __builtin_amdgcn_mfma_f32_16x16x32_bf16(a, b0, acc0, 0, 0, 0);
      acc1 = __builtin_amdgcn_mfma_f32_16x16x32_bf16(a, b1, acc1, 0, 0, 0);
      acc2 = __builtin_amdgcn_mfma_f32_16x16x32_bf16(a, b2, acc2, 0, 0, 0);
      acc3 = __builtin_amdgcn_mfma_f32_16x16x32_bf16(a, b3, acc3, 0, 0, 0);
    }
  }
  const size_t rowb = (size_t)b*LSEQ + yy*WW + x0;
  f32x4 accs[4] = {acc0, acc1, acc2, acc3};
  #pragma unroll
  for (int nt = 0; nt < 4; nt++){
    int co = nt*16 + m;
    if (co < 60){
      float bias = cb[co];
      #pragma unroll
      for (int reg = 0; reg < 4; reg++){
        int px = wave*16 + quad*4 + reg;
        size_t o = (rowb + px)*60 + co;
        out[o] = accs[nt][reg] + bias + xres[o];
      }
    }
  }
}

extern "C" void kernel_launch(void* const* d_in, const int* in_sizes, int n_in,
                              void* d_out, int out_size, void* d_ws, size_t ws_size,
                              hipStream_t stream)
{
  const float* x      = (const float*)d_in[0];
  const float* ln_w   = (const float*)d_in[1];
  const float* ln_b   = (const float*)d_in[2];
  const float* ipw    = (const float*)d_in[3];
  const float* cw     = (const float*)d_in[4];
  const float* cb1    = (const float*)d_in[5];
  const float* xpw    = (const float*)d_in[6];
  const float* dtw    = (const float*)d_in[7];
  const float* dtb    = (const float*)d_in[8];
  const float* A_log  = (const float*)d_in[9];
  const float* Dsk    = (const float*)d_in[10];
  const float* opw    = (const float*)d_in[11];
  const float* c2w    = (const float*)d_in[12];
  const float* c2b    = (const float*)d_in[13];
  float* out = (float*)d_out;

  char* ws = (char*)d_ws;
  size_t off = 0;
  short* zsb   = (short*)(ws + off); off += (size_t)BATCH*LSEQ*DI*2;
  short* xcb   = (short*)(ws + off); off += (size_t)BATCH*LSEQ*DI*2;
  short* dlt   = (short*)(ws + off); off += (size_t)BATCH*LSEQ*DI*2;
  short* BCg   = (short*)(ws + off); off += (size_t)BATCH*LSEQ*32*2;
  float* apb   = (float*)(ws + off); off += (size_t)NCH*BATCH*DI*16*4;
  float* heb   = (float*)(ws + off); off += (size_t)NCH*BATCH*DI*16*4;
  short* hcur  = (short*)(ws + off); off += (size_t)BATCH*LSEQ*DM*2;
  short* wBb   = (short*)(ws + off); off += (size_t)9*64*64*2;
  short* pkb   = (short*)(ws + off); off += (size_t)(2*240*64 + 2*48*128 + 2*64*128)*2;
  float* c01b  = (float*)(ws + off); off += (size_t)2*240*2*4;

  const int rows = BATCH*LSEQ;
  k_pack<<<(59872 + 9*64*64 + 255)/256, 256, 0, stream>>>(ipw, xpw, opw, c2w, ln_w, ln_b, pkb, c01b, wBb);
  for (int layer = 0; layer < 2; layer++){
    const float* srcf = (layer == 0) ? x : nullptr;
    const short* srcb = (layer == 0) ? nullptr : hcur;
    k_lnxp<<<rows/32, 512, 0, stream>>>(srcf, srcb,
                                        pkb + (size_t)layer*240*64,
                                        c01b + (size_t)layer*240*2,
                                        cw + layer*DI*4, cb1 + layer*DI,
                                        pkb + 30720 + (size_t)layer*48*128,
                                        dtw + (size_t)layer*DI*4, dtb + layer*DI,
                                        A_log + (size_t)layer*DI*16,
                                        zsb, xcb, dlt, BCg, apb, heb);
    k_scan2<<<BATCH*DI, 256, 0, stream>>>(apb, heb);
    k_scan3o<<<BATCH*NCH, 256, 0, stream>>>(dlt, xcb, BCg, zsb, apb, A_log + (size_t)layer*DI*16,
                                            Dsk + layer*DI, pkb + 43008 + (size_t)layer*8192, hcur);
  }
  k_conv2d<<<BATCH*HH*2, 256, 0, stream>>>(hcur, wBb, c2b, x, out);
}